// Round 4
// baseline (213.637 us; speedup 1.0000x reference)
//
#include <hip/hip_runtime.h>

// GCN 2-layer forward — 7-kernel + memset pipeline.
// Session rules: in-graph dispatch boundary ~1us (R9); grid.sync ~70us (R8);
// intra-dispatch spin barriers serialize (R10); serial global-memory loops
// are latency poison (R11); fp8 payloads excluded by error budget (R13).
// R16 FAILED (215us): plane-split pullq, row-major h: L2 set-aliasing.
// R17 (209us): plane-major h fixed FETCH (107->25.7MB) but dur 55->49 only:
//      gather is VALU-ISSUE bound, not L2-fill bound (R12 rule FALSIFIED).
//      Inferred: R14 fused pullg ~37us < pullq 49 (plane split pays edge-walk
//      overhead 4x for 1/4 payload). REVERT to fused pullg.
// R18: replace partition+bsort+scanB (suspected 35-50us: scanB=1-block with
//      104 strided loads/thread = latency poison; bsort=196 blocks, <1/CU)
//      with: deg via direct global atomics (in combo's extra blocks) ->
//      3-stage parallel 50K scan -> direct atomic scatter (row order is
//      irrelevant to a sum). Also un-alias h2 (R14 had h2=h race).
// Pipeline: memset(deg) -> L1 combo(gemm1 MFMA || deg atomics) -> scan1 ->
//           scan2 -> scan3 -> scatter -> pullg(pull1+gemm2 fused) -> pull2+lsm

typedef unsigned int uint32;
typedef unsigned short u16;
typedef __attribute__((ext_vector_type(8))) short bf16x8;
typedef __attribute__((ext_vector_type(4))) float f32x4;

#define EH 8192   // edges per deg block

__device__ inline u16 bf16rn(float f) {
    unsigned u = __float_as_uint(f);
    return (u16)((u + 0x7fffu + ((u >> 16) & 1u)) >> 16);
}

__device__ inline void bffma(float2& a, float w, uint32 u) {
    a.x = fmaf(w, __uint_as_float(u << 16), a.x);
    a.y = fmaf(w, __uint_as_float(u & 0xffff0000u), a.y);
}

// ---- L1: gemm1 tiles || per-node degree atomics ---------------------------
__global__ __launch_bounds__(256) void k_combo(
    const float* __restrict__ x, const float* __restrict__ W1,
    const int* __restrict__ dstv, int* __restrict__ deg,
    u16* __restrict__ h, int N, int E, int ntile)
{
    __shared__ __align__(16) unsigned char smem[128 * 136 * 2];  // 34816 B
    int t = threadIdx.x;

    if ((int)blockIdx.x >= ntile) {
        int hb = blockIdx.x - ntile;
        int e0 = hb * EH, e1 = min(e0 + EH, E);
        for (int e = e0 + t; e < e1; e += 256)
            atomicAdd(&deg[dstv[e]], 1);
        return;
    }

    // gemm1: h[N,128](bf16) = x @ W1, MFMA 16x16x32, W1 staged once
    u16* Wl = (u16*)smem;  // [n][k] pitch 136 (2-way bank aliasing: free)
    const float4* Wg4 = (const float4*)W1;
    for (int g = t; g < 128 * 32; g += 256) {
        int k = g >> 5, n4 = (g & 31) * 4;
        float4 v = Wg4[g];
        Wl[(n4 + 0) * 136 + k] = bf16rn(v.x);
        Wl[(n4 + 1) * 136 + k] = bf16rn(v.y);
        Wl[(n4 + 2) * 136 + k] = bf16rn(v.z);
        Wl[(n4 + 3) * 136 + k] = bf16rn(v.w);
    }
    __syncthreads();

    int wave = t >> 6, lane = t & 63;
    int quad = lane >> 4, ln = lane & 15;
    int rowbase = blockIdx.x * 64 + wave * 16;
    int rclamp = min(rowbase + ln, N - 1);

    f32x4 acc[8];
    #pragma unroll
    for (int ct = 0; ct < 8; ++ct) acc[ct] = (f32x4){0.f, 0.f, 0.f, 0.f};

    #pragma unroll
    for (int q = 0; q < 4; ++q) {
        const float4* xr = (const float4*)(x + (size_t)rclamp * 128 + q * 32 + quad * 8);
        float4 a0 = xr[0], a1 = xr[1];
        bf16x8 afr;
        afr[0] = (short)bf16rn(a0.x); afr[1] = (short)bf16rn(a0.y);
        afr[2] = (short)bf16rn(a0.z); afr[3] = (short)bf16rn(a0.w);
        afr[4] = (short)bf16rn(a1.x); afr[5] = (short)bf16rn(a1.y);
        afr[6] = (short)bf16rn(a1.z); afr[7] = (short)bf16rn(a1.w);
        #pragma unroll
        for (int ct = 0; ct < 8; ++ct) {
            bf16x8 bfr = *(const bf16x8*)&Wl[(ct * 16 + ln) * 136 + q * 32 + quad * 8];
            acc[ct] = __builtin_amdgcn_mfma_f32_16x16x32_bf16(afr, bfr, acc[ct], 0, 0, 0);
        }
    }
    #pragma unroll
    for (int i = 0; i < 4; ++i) {
        int r = rowbase + quad * 4 + i;
        if (r < N) {
            u16* hp = h + (size_t)r * 128 + ln;
            #pragma unroll
            for (int ct = 0; ct < 8; ++ct)
                hp[ct * 16] = bf16rn(acc[ct][i]);
        }
    }
}

// ---- L2a: per-256-bucket inclusive scan of deg; dinv; bucket sums ---------
__global__ __launch_bounds__(256) void k_scan1(
    const int* __restrict__ deg, int* __restrict__ rs,
    float* __restrict__ dinv, int* __restrict__ bsum, int N)
{
    __shared__ int s[256];
    int t = threadIdx.x;
    int n = blockIdx.x * 256 + t;
    int d = (n < N) ? deg[n] : 0;
    s[t] = d;
    __syncthreads();
    for (int off = 1; off < 256; off <<= 1) {
        int u = (t >= off) ? s[t - off] : 0;
        __syncthreads();
        s[t] += u;
        __syncthreads();
    }
    if (n < N) {
        rs[n] = s[t];                      // bucket-local inclusive
        dinv[n] = rsqrtf(fmaxf((float)d, 1.0f));
    }
    if (t == 255) bsum[blockIdx.x] = s[255];
}

// ---- L2b: exclusive scan of bucket sums (single small block) --------------
__global__ __launch_bounds__(256) void k_scan2(
    const int* __restrict__ bsum, int* __restrict__ bofs, int NBg)
{
    __shared__ int s[256];
    int t = threadIdx.x;
    int v = (t < NBg) ? bsum[t] : 0;
    s[t] = v;
    __syncthreads();
    for (int off = 1; off < 256; off <<= 1) {
        int u = (t >= off) ? s[t - off] : 0;
        __syncthreads();
        s[t] += u;
        __syncthreads();
    }
    bofs[t] = s[t] - v;
}

// ---- L2c: add-back -> absolute rs; row starts; zero fill ------------------
__global__ __launch_bounds__(256) void k_scan3(
    int* __restrict__ rs, const int* __restrict__ deg,
    const int* __restrict__ bofs, int* __restrict__ sta,
    int* __restrict__ fill, int N)
{
    int n = blockIdx.x * 256 + threadIdx.x;
    if (n >= N) return;
    int r = rs[n] + bofs[n >> 8];
    rs[n] = r;                 // inclusive end
    sta[n] = r - deg[n];       // row start
    fill[n] = 0;
}

// ---- L3: direct atomic scatter to CSR (order within row irrelevant) -------
__global__ __launch_bounds__(256) void k_scatter(
    const int* __restrict__ src, const int* __restrict__ dstv,
    const int* __restrict__ sta, int* __restrict__ fill,
    u16* __restrict__ ssrc, int E)
{
    int e = blockIdx.x * 256 + threadIdx.x;
    if (e >= E) return;
    int s = src[e], d = dstv[e];
    int pos = sta[d] + atomicAdd(&fill[d], 1);
    ssrc[pos] = (u16)s;
}

// ---- L5: pullg — fused pull1 + gemm2 (R14 structure, h2 un-aliased) -------
__global__ __launch_bounds__(256) void k_pullg(
    const int* __restrict__ rs, const u16* __restrict__ ssrc,
    const float* __restrict__ dinv, const uint2* __restrict__ h,
    const float* __restrict__ b1, const float* __restrict__ W2,
    u16* __restrict__ h2, int N)
{
    __shared__ float W2T[16 * 132];   // [f][k] pitch 132
    __shared__ float rowbuf[8 * 132]; // [r][k] pitch 132 (float4 pitch 33)
    int t = threadIdx.x;

    for (int g = t; g < 2048; g += 256) {
        int k = g >> 4, f = g & 15;
        W2T[f * 132 + k] = W2[g];
    }

    int wave = t >> 6, lane = t & 63;
    int sub = lane >> 5;
    int rl = lane & 31;
    int rowbase = blockIdx.x * 8;
    int n = rowbase + wave * 2 + sub;
    bool valid = (n < N);
    int nc = valid ? n : 0;
    int start = valid ? ((nc == 0) ? 0 : rs[nc - 1]) : 0;
    int len   = valid ? (rs[nc] - start) : 0;
    float dn  = valid ? dinv[nc] : 0.f;
    int lenMax = max(len, __shfl_xor(len, 32));

    float2 aA[4], aB[4];
    #pragma unroll
    for (int k = 0; k < 4; ++k) {
        aA[k] = (float2){0.f, 0.f};
        aB[k] = (float2){0.f, 0.f};
    }

    for (int tt = 0; tt < lenMax; tt += 4) {
        int s[4];
        uint2 u[4];
        float w[4];
        #pragma unroll
        for (int k = 0; k < 4; ++k) {
            bool act = (tt + k) < len;
            int jj = act ? (start + tt + k) : 0;
            s[k] = (int)ssrc[jj];
            w[k] = act ? 1.f : 0.f;
        }
        #pragma unroll
        for (int k = 0; k < 4; ++k)
            u[k] = h[(size_t)s[k] * 32 + rl];
        #pragma unroll
        for (int k = 0; k < 4; ++k)
            w[k] *= dn * dinv[s[k]];
        #pragma unroll
        for (int k = 0; k < 4; ++k) {
            bffma(aA[k], w[k], u[k].x);
            bffma(aB[k], w[k], u[k].y);
        }
    }

    {
        int r = wave * 2 + sub;
        float4 bb = ((const float4*)b1)[rl];
        float4 v;
        v.x = fmaxf(((aA[0].x + aA[1].x) + (aA[2].x + aA[3].x)) + bb.x, 0.f);
        v.y = fmaxf(((aA[0].y + aA[1].y) + (aA[2].y + aA[3].y)) + bb.y, 0.f);
        v.z = fmaxf(((aB[0].x + aB[1].x) + (aB[2].x + aB[3].x)) + bb.z, 0.f);
        v.w = fmaxf(((aB[0].y + aB[1].y) + (aB[2].y + aB[3].y)) + bb.w, 0.f);
        ((float4*)rowbuf)[r * 33 + rl] = v;
    }
    __syncthreads();

    if (t < 128) {
        int f = t & 15, r = t >> 4;
        const float4* W4 = (const float4*)W2T;
        const float4* rb4 = (const float4*)rowbuf;
        float acc = 0.f;
        #pragma unroll 8
        for (int k4 = 0; k4 < 32; ++k4) {
            float4 w = W4[f * 33 + k4];
            float4 xv = rb4[r * 33 + k4];
            acc = fmaf(xv.x, w.x, acc);
            acc = fmaf(xv.y, w.y, acc);
            acc = fmaf(xv.z, w.z, acc);
            acc = fmaf(xv.w, w.w, acc);
        }
        int rn = rowbase + r;
        if (rn < N) h2[(size_t)rn * 16 + f] = bf16rn(acc);
    }
}

// ---- L6: pull2 + log_softmax, 4-deep unroll -------------------------------
__global__ __launch_bounds__(256) void k_pull2(
    const int* __restrict__ rs, const u16* __restrict__ ssrc,
    const float* __restrict__ dinv, const uint32* __restrict__ h2,
    const float* __restrict__ b2, float* __restrict__ out, int N)
{
    int idx = blockIdx.x * 256 + threadIdx.x;
    int n = idx >> 3;
    if (n >= N) return;
    int c = idx & 7;
    int start = (n == 0) ? 0 : rs[n - 1];
    int len = rs[n] - start;
    float dn = dinv[n];

    float2 a[4];
    #pragma unroll
    for (int k = 0; k < 4; ++k) a[k] = (float2){0.f, 0.f};

    for (int tt = 0; tt < len; tt += 4) {
        int s[4];
        uint32 u[4];
        float w[4];
        #pragma unroll
        for (int k = 0; k < 4; ++k) {
            bool act = (tt + k) < len;
            int jj = act ? (start + tt + k) : 0;   // index 0 always valid
            s[k] = (int)ssrc[jj];
            w[k] = act ? 1.f : 0.f;
        }
        #pragma unroll
        for (int k = 0; k < 4; ++k)
            u[k] = h2[(size_t)s[k] * 8 + c];
        #pragma unroll
        for (int k = 0; k < 4; ++k)
            w[k] *= dn * dinv[s[k]];
        #pragma unroll
        for (int k = 0; k < 4; ++k)
            bffma(a[k], w[k], u[k]);
    }

    float acc0 = (a[0].x + a[1].x) + (a[2].x + a[3].x);
    float acc1 = (a[0].y + a[1].y) + (a[2].y + a[3].y);
    float v0 = acc0 + b2[2 * c];
    float v1 = acc1 + b2[2 * c + 1];
    float m = fmaxf(v0, v1);
    #pragma unroll
    for (int off = 1; off < 8; off <<= 1) m = fmaxf(m, __shfl_xor(m, off));
    float s = expf(v0 - m) + expf(v1 - m);
    #pragma unroll
    for (int off = 1; off < 8; off <<= 1) s += __shfl_xor(s, off);
    float ls = logf(s);
    float2 r = {v0 - m - ls, v1 - m - ls};
    ((float2*)out)[(size_t)n * 8 + c] = r;
}

extern "C" void kernel_launch(void* const* d_in, const int* in_sizes, int n_in,
                              void* d_out, int out_size, void* d_ws, size_t ws_size,
                              hipStream_t stream) {
    const float* x  = (const float*)d_in[0];
    const int*   ei = (const int*)d_in[1];
    const float* W1 = (const float*)d_in[2];
    const float* b1 = (const float*)d_in[3];
    const float* W2 = (const float*)d_in[4];
    const float* b2 = (const float*)d_in[5];
    float* outp = (float*)d_out;

    const int E = in_sizes[1] / 2;
    const int N = in_sizes[0] / 128;   // N=50000 (fits u16 src packing)
    const int NB = (N + 255) >> 8;     // 256-node buckets for the scan
    const int NH = (E + EH - 1) / EH;  // deg blocks
    const int ntile = (N + 63) / 64;
    const int* src  = ei;
    const int* dstv = ei + E;

    const int Npad = (N + 255) & ~255;
    const int Epad = (E + 255) & ~255;
    int*   deg  = (int*)d_ws;                       // [Npad]
    int*   rs   = deg + Npad;                       // [Npad] inclusive ends
    int*   sta  = rs + Npad;                        // [Npad] row starts
    int*   fill = sta + Npad;                       // [Npad]
    int*   bsum = fill + Npad;                      // [256]
    int*   bofs = bsum + 256;                       // [256]
    float* dinv = (float*)(bofs + 256);             // [Npad]
    u16*   ssrc = (u16*)(dinv + Npad);              // [Epad]
    uintptr_t hp = ((uintptr_t)(ssrc + Epad) + 255) & ~(uintptr_t)255;
    u16*   h    = (u16*)hp;                         // [Npad*128] bf16
    u16*   h2   = h + (size_t)Npad * 128;           // [Npad*16] bf16

    hipMemsetAsync(deg, 0, (size_t)Npad * sizeof(int), stream);
    k_combo<<<ntile + NH, 256, 0, stream>>>(x, W1, dstv, deg, h, N, E, ntile);
    k_scan1<<<NB, 256, 0, stream>>>(deg, rs, dinv, bsum, N);
    k_scan2<<<1, 256, 0, stream>>>(bsum, bofs, NB);
    k_scan3<<<NB, 256, 0, stream>>>(rs, deg, bofs, sta, fill, N);
    k_scatter<<<(E + 255) / 256, 256, 0, stream>>>(src, dstv, sta, fill, ssrc, E);
    k_pullg<<<(N + 7) / 8, 256, 0, stream>>>(rs, ssrc, dinv, (const uint2*)h,
                                             b1, W2, h2, N);
    k_pull2<<<(N * 8 + 255) / 256, 256, 0, stream>>>(rs, ssrc, dinv,
                                                     (const uint32*)h2, b2, outp, N);
}

// Round 5
// 189.570 us; speedup vs baseline: 1.1270x; 1.1270x over previous
//
#include <hip/hip_runtime.h>

// GCN 2-layer forward — 6-dispatch pipeline.
// Session rules: in-graph dispatch boundary ~1us (R9); grid.sync ~70us (R8);
// intra-dispatch spin barriers serialize (R10); serial global-memory loops
// are latency poison (R11) — BUT R18 falsified the scanB case: old chain
// (scanB+partition+bsort) beats global-atomic deg+scatter by ~23us. Bulk
// random device atomics are the real poison (R18). Gather is VALU-issue
// bound, not L2-fill bound (R17, falsifies R12). fp8 excluded (R13).
// R16 FAIL 215us (plane-split pullq); R17 209us; R18 FAIL 213.6us (atomic
// CSR chain; also exposed combo = 46.5us @ 1% MFMA, WRITE 37.6MB vs 13 ideal
// from 32x per-thread scalar u16 C-stores).
// R19: revert to R15 structure (190.8us proven) + ONE delta: gemm1 MFMA
// operand swap -> D[feature][node], so each lane owns 4 consecutive features
// of one node -> C-writeback = 8x store_dwordx2 (was 32x store_short).
// Also h2 un-aliased from h (removes latent race, costs nothing).
// Pipeline: L1 combo(gemm1 MFMA || hist partials) -> L2 scanB -> L3 partition
//           -> L4 bsort -> L5 pullg(pull1+gemm2 fused) -> L6 pull2+lsm

typedef unsigned int uint32;
typedef unsigned short u16;
typedef __attribute__((ext_vector_type(8))) short bf16x8;
typedef __attribute__((ext_vector_type(4))) float f32x4;

#define NBMAX 1024
#define CHUNK 4096
#define EH 8192   // edges per hist block

__device__ inline u16 bf16rn(float f) {
    unsigned u = __float_as_uint(f);
    return (u16)((u + 0x7fffu + ((u >> 16) & 1u)) >> 16);
}

__device__ inline void bffma(float2& a, float w, uint32 u) {
    a.x = fmaf(w, __uint_as_float(u << 16), a.x);
    a.y = fmaf(w, __uint_as_float(u & 0xffff0000u), a.y);
}

// ---- L1: gemm1 tiles || hist partial histograms ---------------------------
__global__ __launch_bounds__(256) void k_combo(
    const float* __restrict__ x, const float* __restrict__ W1,
    const int* __restrict__ dstv, int* __restrict__ partials,
    u16* __restrict__ h, int N, int E, int NB, int ntile)
{
    __shared__ __align__(16) unsigned char smem[128 * 136 * 2];  // 34816 B
    int t = threadIdx.x;

    if ((int)blockIdx.x >= ntile) {
        int* hl = (int*)smem;
        int hb = blockIdx.x - ntile;
        int e0 = hb * EH, e1 = min(e0 + EH, E);
        for (int i = t; i < NB; i += 256) hl[i] = 0;
        __syncthreads();
        for (int e = e0 + t; e < e1; e += 256)
            atomicAdd(&hl[dstv[e] >> 8], 1);
        __syncthreads();
        int* pr = partials + (size_t)hb * NBMAX;
        for (int i = t; i < NB; i += 256) pr[i] = hl[i];
        return;
    }

    // gemm1: h[N,128](bf16) = x @ W1, MFMA 16x16x32 with operands SWAPPED:
    // D[feature][node], A-frag = W (row=feature-in-block), B-frag = x (col=node).
    // Lane (quad,ln): node = rowbase+ln; owns features ct*16 + quad*4 + i.
    u16* Wl = (u16*)smem;  // [n][k] pitch 136 (2-way bank aliasing: free)
    const float4* Wg4 = (const float4*)W1;
    for (int g = t; g < 128 * 32; g += 256) {
        int k = g >> 5, n4 = (g & 31) * 4;
        float4 v = Wg4[g];
        Wl[(n4 + 0) * 136 + k] = bf16rn(v.x);
        Wl[(n4 + 1) * 136 + k] = bf16rn(v.y);
        Wl[(n4 + 2) * 136 + k] = bf16rn(v.z);
        Wl[(n4 + 3) * 136 + k] = bf16rn(v.w);
    }
    __syncthreads();

    int wave = t >> 6, lane = t & 63;
    int quad = lane >> 4, ln = lane & 15;
    int rowbase = blockIdx.x * 64 + wave * 16;
    int node = rowbase + ln;
    int rclamp = min(node, N - 1);

    f32x4 acc[8];
    #pragma unroll
    for (int ct = 0; ct < 8; ++ct) acc[ct] = (f32x4){0.f, 0.f, 0.f, 0.f};

    #pragma unroll
    for (int q = 0; q < 4; ++q) {
        const float4* xr = (const float4*)(x + (size_t)rclamp * 128 + q * 32 + quad * 8);
        float4 a0 = xr[0], a1 = xr[1];
        bf16x8 xfr;   // B-operand: col=node(ln), k = q*32 + quad*8 + e
        xfr[0] = (short)bf16rn(a0.x); xfr[1] = (short)bf16rn(a0.y);
        xfr[2] = (short)bf16rn(a0.z); xfr[3] = (short)bf16rn(a0.w);
        xfr[4] = (short)bf16rn(a1.x); xfr[5] = (short)bf16rn(a1.y);
        xfr[6] = (short)bf16rn(a1.z); xfr[7] = (short)bf16rn(a1.w);
        #pragma unroll
        for (int ct = 0; ct < 8; ++ct) {
            // A-operand: row=feature-in-block(ln), k = q*32 + quad*8 + e
            bf16x8 wfr = *(const bf16x8*)&Wl[(ct * 16 + ln) * 136 + q * 32 + quad * 8];
            acc[ct] = __builtin_amdgcn_mfma_f32_16x16x32_bf16(wfr, xfr, acc[ct], 0, 0, 0);
        }
    }
    // writeback: lane owns node=rowbase+ln, features ct*16+quad*4+{0..3}
    if (node < N) {
        u16* hp = h + (size_t)node * 128 + quad * 4;
        #pragma unroll
        for (int ct = 0; ct < 8; ++ct) {
            uint2 v;
            v.x = (uint32)bf16rn(acc[ct][0]) | ((uint32)bf16rn(acc[ct][1]) << 16);
            v.y = (uint32)bf16rn(acc[ct][2]) | ((uint32)bf16rn(acc[ct][3]) << 16);
            *(uint2*)(hp + ct * 16) = v;
        }
    }
}

// ---- L2: reduce partials, exclusive scan, zero bfill ----------------------
__global__ __launch_bounds__(1024) void k_scanB(
    const int* __restrict__ partials, int* __restrict__ bbase,
    int* __restrict__ bfill, int NB, int E, int NH)
{
    __shared__ int s[1024];
    int t = threadIdx.x;
    int v = 0;
    if (t < NB)
        for (int p = 0; p < NH; ++p) v += partials[(size_t)p * NBMAX + t];
    s[t] = v;
    __syncthreads();
    for (int off = 1; off < 1024; off <<= 1) {
        int u = (t >= off) ? s[t - off] : 0;
        __syncthreads();
        s[t] += u;
        __syncthreads();
    }
    if (t < NB) {
        bbase[t] = s[t] - v;
        bfill[t] = 0;
    }
    if (t == 0) bbase[NB] = E;
}

// ---- L3: partition edges into bucket regions (packed u32 records) ---------
__global__ __launch_bounds__(256) void k_partition(
    const int* __restrict__ src, const int* __restrict__ dstv,
    const int* __restrict__ bbase, int* __restrict__ bfill,
    uint32* __restrict__ tmp, int E, int NB)
{
    __shared__ int cntL[NBMAX];
    __shared__ int baseL[NBMAX];
    int t = threadIdx.x;
    int e0 = blockIdx.x * CHUNK;
    int e1 = min(e0 + CHUNK, E);
    for (int i = t; i < NB; i += 256) cntL[i] = 0;
    __syncthreads();
    for (int e = e0 + t; e < e1; e += 256)
        atomicAdd(&cntL[dstv[e] >> 8], 1);
    __syncthreads();
    for (int i = t; i < NB; i += 256) {
        int cc = cntL[i];
        baseL[i] = cc ? bbase[i] + atomicAdd(&bfill[i], cc) : 0;
        cntL[i] = 0;
    }
    __syncthreads();
    for (int e = e0 + t; e < e1; e += 256) {
        int sv = src[e], d = dstv[e];
        int b = d >> 8;
        int r = atomicAdd(&cntL[b], 1);
        tmp[baseL[b] + r] = (uint32)sv | ((uint32)(d & 255) << 16);
    }
}

// ---- L4: per-bucket exact sort; emit dinv / rs / ssrc(u16) ----------------
__global__ __launch_bounds__(256) void k_bsort(
    const uint32* __restrict__ tmp, const int* __restrict__ bbase,
    u16* __restrict__ ssrc, int* __restrict__ rs,
    float* __restrict__ dinv, int N)
{
    __shared__ int cnt[256];
    __shared__ int ofs[256];
    int t = threadIdx.x;
    int b = blockIdx.x;
    int base = bbase[b];
    int endb = bbase[b + 1];
    int node0 = b << 8;

    cnt[t] = 0;
    __syncthreads();
    for (int i = base + t; i < endb; i += 256)
        atomicAdd(&cnt[(tmp[i] >> 16) & 255], 1);
    __syncthreads();
    int v = cnt[t];
    __syncthreads();
    for (int off = 1; off < 256; off <<= 1) {
        int u = (t >= off) ? cnt[t - off] : 0;
        __syncthreads();
        cnt[t] += u;
        __syncthreads();
    }
    int node = node0 + t;
    if (node < N) {
        dinv[node] = rsqrtf(fmaxf((float)v, 1.0f));
        rs[node] = base + cnt[t];
    }
    ofs[t] = base + cnt[t] - v;
    __syncthreads();
    for (int i = base + t; i < endb; i += 256) {
        uint32 rec = tmp[i];
        int pos = atomicAdd(&ofs[(rec >> 16) & 255], 1);
        ssrc[pos] = (u16)(rec & 0xffffu);
    }
}

// ---- L5: pullg — fused pull1 + gemm2 --------------------------------------
__global__ __launch_bounds__(256) void k_pullg(
    const int* __restrict__ rs, const u16* __restrict__ ssrc,
    const float* __restrict__ dinv, const uint2* __restrict__ h,
    const float* __restrict__ b1, const float* __restrict__ W2,
    u16* __restrict__ h2, int N)
{
    __shared__ float W2T[16 * 132];   // [f][k] pitch 132
    __shared__ float rowbuf[8 * 132]; // [r][k] pitch 132 (float4 pitch 33)
    int t = threadIdx.x;

    for (int g = t; g < 2048; g += 256) {
        int k = g >> 4, f = g & 15;
        W2T[f * 132 + k] = W2[g];
    }

    int wave = t >> 6, lane = t & 63;
    int sub = lane >> 5;
    int rl = lane & 31;
    int rowbase = blockIdx.x * 8;
    int n = rowbase + wave * 2 + sub;
    bool valid = (n < N);
    int nc = valid ? n : 0;
    int start = valid ? ((nc == 0) ? 0 : rs[nc - 1]) : 0;
    int len   = valid ? (rs[nc] - start) : 0;
    float dn  = valid ? dinv[nc] : 0.f;
    int lenMax = max(len, __shfl_xor(len, 32));

    float2 aA[4], aB[4];
    #pragma unroll
    for (int k = 0; k < 4; ++k) {
        aA[k] = (float2){0.f, 0.f};
        aB[k] = (float2){0.f, 0.f};
    }

    for (int tt = 0; tt < lenMax; tt += 4) {
        int s[4];
        uint2 u[4];
        float w[4];
        #pragma unroll
        for (int k = 0; k < 4; ++k) {
            bool act = (tt + k) < len;
            int jj = act ? (start + tt + k) : 0;
            s[k] = (int)ssrc[jj];
            w[k] = act ? 1.f : 0.f;
        }
        #pragma unroll
        for (int k = 0; k < 4; ++k)
            u[k] = h[(size_t)s[k] * 32 + rl];
        #pragma unroll
        for (int k = 0; k < 4; ++k)
            w[k] *= dn * dinv[s[k]];
        #pragma unroll
        for (int k = 0; k < 4; ++k) {
            bffma(aA[k], w[k], u[k].x);
            bffma(aB[k], w[k], u[k].y);
        }
    }

    {
        int r = wave * 2 + sub;
        float4 bb = ((const float4*)b1)[rl];
        float4 v;
        v.x = fmaxf(((aA[0].x + aA[1].x) + (aA[2].x + aA[3].x)) + bb.x, 0.f);
        v.y = fmaxf(((aA[0].y + aA[1].y) + (aA[2].y + aA[3].y)) + bb.y, 0.f);
        v.z = fmaxf(((aB[0].x + aB[1].x) + (aB[2].x + aB[3].x)) + bb.z, 0.f);
        v.w = fmaxf(((aB[0].y + aB[1].y) + (aB[2].y + aB[3].y)) + bb.w, 0.f);
        ((float4*)rowbuf)[r * 33 + rl] = v;
    }
    __syncthreads();

    if (t < 128) {
        int f = t & 15, r = t >> 4;
        const float4* W4 = (const float4*)W2T;
        const float4* rb4 = (const float4*)rowbuf;
        float acc = 0.f;
        #pragma unroll 8
        for (int k4 = 0; k4 < 32; ++k4) {
            float4 w = W4[f * 33 + k4];
            float4 xv = rb4[r * 33 + k4];
            acc = fmaf(xv.x, w.x, acc);
            acc = fmaf(xv.y, w.y, acc);
            acc = fmaf(xv.z, w.z, acc);
            acc = fmaf(xv.w, w.w, acc);
        }
        int rn = rowbase + r;
        if (rn < N) h2[(size_t)rn * 16 + f] = bf16rn(acc);
    }
}

// ---- L6: pull2 + log_softmax, 4-deep unroll -------------------------------
__global__ __launch_bounds__(256) void k_pull2(
    const int* __restrict__ rs, const u16* __restrict__ ssrc,
    const float* __restrict__ dinv, const uint32* __restrict__ h2,
    const float* __restrict__ b2, float* __restrict__ out, int N)
{
    int idx = blockIdx.x * 256 + threadIdx.x;
    int n = idx >> 3;
    if (n >= N) return;
    int c = idx & 7;
    int start = (n == 0) ? 0 : rs[n - 1];
    int len = rs[n] - start;
    float dn = dinv[n];

    float2 a[4];
    #pragma unroll
    for (int k = 0; k < 4; ++k) a[k] = (float2){0.f, 0.f};

    for (int tt = 0; tt < len; tt += 4) {
        int s[4];
        uint32 u[4];
        float w[4];
        #pragma unroll
        for (int k = 0; k < 4; ++k) {
            bool act = (tt + k) < len;
            int jj = act ? (start + tt + k) : 0;   // index 0 always valid
            s[k] = (int)ssrc[jj];
            w[k] = act ? 1.f : 0.f;
        }
        #pragma unroll
        for (int k = 0; k < 4; ++k)
            u[k] = h2[(size_t)s[k] * 8 + c];
        #pragma unroll
        for (int k = 0; k < 4; ++k)
            w[k] *= dn * dinv[s[k]];
        #pragma unroll
        for (int k = 0; k < 4; ++k)
            bffma(a[k], w[k], u[k]);
    }

    float acc0 = (a[0].x + a[1].x) + (a[2].x + a[3].x);
    float acc1 = (a[0].y + a[1].y) + (a[2].y + a[3].y);
    float v0 = acc0 + b2[2 * c];
    float v1 = acc1 + b2[2 * c + 1];
    float m = fmaxf(v0, v1);
    #pragma unroll
    for (int off = 1; off < 8; off <<= 1) m = fmaxf(m, __shfl_xor(m, off));
    float s = expf(v0 - m) + expf(v1 - m);
    #pragma unroll
    for (int off = 1; off < 8; off <<= 1) s += __shfl_xor(s, off);
    float ls = logf(s);
    float2 r = {v0 - m - ls, v1 - m - ls};
    ((float2*)out)[(size_t)n * 8 + c] = r;
}

extern "C" void kernel_launch(void* const* d_in, const int* in_sizes, int n_in,
                              void* d_out, int out_size, void* d_ws, size_t ws_size,
                              hipStream_t stream) {
    const float* x  = (const float*)d_in[0];
    const int*   ei = (const int*)d_in[1];
    const float* W1 = (const float*)d_in[2];
    const float* b1 = (const float*)d_in[3];
    const float* W2 = (const float*)d_in[4];
    const float* b2 = (const float*)d_in[5];
    float* outp = (float*)d_out;

    const int E = in_sizes[1] / 2;
    const int N = in_sizes[0] / 128;   // N=50000 (fits u16 src packing)
    const int NB = (N + 255) >> 8;
    const int NH = (E + EH - 1) / EH;
    const int ntile = (N + 63) / 64;
    const int* src  = ei;
    const int* dstv = ei + E;

    const int Npad = (N + 255) & ~255;
    const int Epad = (E + 255) & ~255;
    int*   partials = (int*)d_ws;                   // [NH(<=128)][NBMAX]
    int*   bbase = partials + 128 * NBMAX;          // [NBMAX+1] (+pad)
    int*   bfill = bbase + NBMAX + 256;             // [NBMAX]
    int*   rs    = bfill + NBMAX;                   // [Npad]
    float* dinv  = (float*)(rs + Npad);             // [Npad]
    uint32* tmp  = (uint32*)(dinv + Npad);          // [Epad] packed src|dstlow
    u16*   ssrc  = (u16*)(tmp + Epad);              // [Epad] u16
    uintptr_t hp = ((uintptr_t)(ssrc + Epad) + 255) & ~(uintptr_t)255;
    u16*   h     = (u16*)hp;                        // [Npad*128] bf16
    u16*   h2    = h + (size_t)Npad * 128;          // [Npad*16] bf16 (un-aliased)

    k_combo<<<ntile + NH, 256, 0, stream>>>(x, W1, dstv, partials, h, N, E, NB, ntile);
    k_scanB<<<1, 1024, 0, stream>>>(partials, bbase, bfill, NB, E, NH);
    k_partition<<<(E + CHUNK - 1) / CHUNK, 256, 0, stream>>>(src, dstv, bbase,
                                                             bfill, tmp, E, NB);
    k_bsort<<<NB, 256, 0, stream>>>(tmp, bbase, ssrc, rs, dinv, N);
    k_pullg<<<(N + 7) / 8, 256, 0, stream>>>(rs, ssrc, dinv, (const uint2*)h,
                                             b1, W2, h2, N);
    k_pull2<<<(N * 8 + 255) / 256, 256, 0, stream>>>(rs, ssrc, dinv,
                                                     (const uint32*)h2, b2, outp, N);
}

// Round 6
// 172.121 us; speedup vs baseline: 1.2412x; 1.1014x over previous
//
#include <hip/hip_runtime.h>

// GCN 2-layer forward — 6-dispatch (+4KB memset) pipeline.
// Session rules: in-graph dispatch boundary ~1us (R9); grid.sync ~70us (R8);
// intra-dispatch spin barriers serialize (R10); serial global loops are
// latency poison (R11); BULK (100K+) random device atomics are poison, small
// counts (~20K) fine (R18); gather is VALU-issue bound not L2-fill bound
// (R17); fp8 excluded (R13).
// R16 FAIL 215 (plane-split pullq); R17 209; R18 FAIL 213.6 (atomic CSR;
// combo 46.5us reading was deg-atomic pollution, not store cost — see R19).
// R19 (189.6us, best): operand-swapped gemm1 D[feat][node] -> dwordx2 stores.
// R20: mid-chain latency fixes, 3 independent deltas, nothing else touched:
//   a) hist blocks merge LDS hists into global gh via ~196 atomics/block
//      (~20K total) -> scanB loses its serial NH=104 load loop (R11 poison),
//      becomes load+scan+store (~2us). partials array deleted.
//   b) partition: 256 -> 512 threads/block (1->2 waves/SIMD, halves exposed-
//      latency iterations).
//   c) bsort: 256 -> 512 threads/block (same mechanism; scan guarded t<256).
// Pipeline: memset(gh) -> L1 combo(gemm1 MFMA || hist->gh) -> L2 scanB ->
//           L3 partition -> L4 bsort -> L5 pullg -> L6 pull2+lsm

typedef unsigned int uint32;
typedef unsigned short u16;
typedef __attribute__((ext_vector_type(8))) short bf16x8;
typedef __attribute__((ext_vector_type(4))) float f32x4;

#define NBMAX 1024
#define CHUNK 4096
#define EH 8192   // edges per hist block

__device__ inline u16 bf16rn(float f) {
    unsigned u = __float_as_uint(f);
    return (u16)((u + 0x7fffu + ((u >> 16) & 1u)) >> 16);
}

__device__ inline void bffma(float2& a, float w, uint32 u) {
    a.x = fmaf(w, __uint_as_float(u << 16), a.x);
    a.y = fmaf(w, __uint_as_float(u & 0xffff0000u), a.y);
}

// ---- L1: gemm1 tiles || hist blocks (LDS hist -> global gh atomics) -------
__global__ __launch_bounds__(256) void k_combo(
    const float* __restrict__ x, const float* __restrict__ W1,
    const int* __restrict__ dstv, int* __restrict__ gh,
    u16* __restrict__ h, int N, int E, int NB, int ntile)
{
    __shared__ __align__(16) unsigned char smem[128 * 136 * 2];  // 34816 B
    int t = threadIdx.x;

    if ((int)blockIdx.x >= ntile) {
        int* hl = (int*)smem;
        int hb = blockIdx.x - ntile;
        int e0 = hb * EH, e1 = min(e0 + EH, E);
        for (int i = t; i < NB; i += 256) hl[i] = 0;
        __syncthreads();
        for (int e = e0 + t; e < e1; e += 256)
            atomicAdd(&hl[dstv[e] >> 8], 1);
        __syncthreads();
        for (int i = t; i < NB; i += 256) {
            int c = hl[i];
            if (c) atomicAdd(&gh[i], c);   // ~196 device atomics/block (cheap)
        }
        return;
    }

    // gemm1: h[N,128](bf16) = x @ W1, MFMA 16x16x32, operands swapped:
    // D[feature][node]; lane owns node=rowbase+ln, features ct*16+quad*4+i.
    u16* Wl = (u16*)smem;  // [n][k] pitch 136 (2-way bank aliasing: free)
    const float4* Wg4 = (const float4*)W1;
    for (int g = t; g < 128 * 32; g += 256) {
        int k = g >> 5, n4 = (g & 31) * 4;
        float4 v = Wg4[g];
        Wl[(n4 + 0) * 136 + k] = bf16rn(v.x);
        Wl[(n4 + 1) * 136 + k] = bf16rn(v.y);
        Wl[(n4 + 2) * 136 + k] = bf16rn(v.z);
        Wl[(n4 + 3) * 136 + k] = bf16rn(v.w);
    }
    __syncthreads();

    int wave = t >> 6, lane = t & 63;
    int quad = lane >> 4, ln = lane & 15;
    int rowbase = blockIdx.x * 64 + wave * 16;
    int node = rowbase + ln;
    int rclamp = min(node, N - 1);

    f32x4 acc[8];
    #pragma unroll
    for (int ct = 0; ct < 8; ++ct) acc[ct] = (f32x4){0.f, 0.f, 0.f, 0.f};

    #pragma unroll
    for (int q = 0; q < 4; ++q) {
        const float4* xr = (const float4*)(x + (size_t)rclamp * 128 + q * 32 + quad * 8);
        float4 a0 = xr[0], a1 = xr[1];
        bf16x8 xfr;   // B-operand: col=node(ln), k = q*32 + quad*8 + e
        xfr[0] = (short)bf16rn(a0.x); xfr[1] = (short)bf16rn(a0.y);
        xfr[2] = (short)bf16rn(a0.z); xfr[3] = (short)bf16rn(a0.w);
        xfr[4] = (short)bf16rn(a1.x); xfr[5] = (short)bf16rn(a1.y);
        xfr[6] = (short)bf16rn(a1.z); xfr[7] = (short)bf16rn(a1.w);
        #pragma unroll
        for (int ct = 0; ct < 8; ++ct) {
            // A-operand: row=feature-in-block(ln), k = q*32 + quad*8 + e
            bf16x8 wfr = *(const bf16x8*)&Wl[(ct * 16 + ln) * 136 + q * 32 + quad * 8];
            acc[ct] = __builtin_amdgcn_mfma_f32_16x16x32_bf16(wfr, xfr, acc[ct], 0, 0, 0);
        }
    }
    if (node < N) {
        u16* hp = h + (size_t)node * 128 + quad * 4;
        #pragma unroll
        for (int ct = 0; ct < 8; ++ct) {
            uint2 v;
            v.x = (uint32)bf16rn(acc[ct][0]) | ((uint32)bf16rn(acc[ct][1]) << 16);
            v.y = (uint32)bf16rn(acc[ct][2]) | ((uint32)bf16rn(acc[ct][3]) << 16);
            *(uint2*)(hp + ct * 16) = v;
        }
    }
}

// ---- L2: exclusive scan of gh, zero bfill (serial reduce eliminated) ------
__global__ __launch_bounds__(1024) void k_scanB(
    const int* __restrict__ gh, int* __restrict__ bbase,
    int* __restrict__ bfill, int NB, int E)
{
    __shared__ int s[1024];
    int t = threadIdx.x;
    int v = (t < NB) ? gh[t] : 0;
    s[t] = v;
    __syncthreads();
    for (int off = 1; off < 1024; off <<= 1) {
        int u = (t >= off) ? s[t - off] : 0;
        __syncthreads();
        s[t] += u;
        __syncthreads();
    }
    if (t < NB) {
        bbase[t] = s[t] - v;
        bfill[t] = 0;
    }
    if (t == 0) bbase[NB] = E;
}

// ---- L3: partition edges into bucket regions (512 threads/block) ----------
__global__ __launch_bounds__(512) void k_partition(
    const int* __restrict__ src, const int* __restrict__ dstv,
    const int* __restrict__ bbase, int* __restrict__ bfill,
    uint32* __restrict__ tmp, int E, int NB)
{
    __shared__ int cntL[NBMAX];
    __shared__ int baseL[NBMAX];
    int t = threadIdx.x;
    int e0 = blockIdx.x * CHUNK;
    int e1 = min(e0 + CHUNK, E);
    for (int i = t; i < NB; i += 512) cntL[i] = 0;
    __syncthreads();
    for (int e = e0 + t; e < e1; e += 512)
        atomicAdd(&cntL[dstv[e] >> 8], 1);
    __syncthreads();
    for (int i = t; i < NB; i += 512) {
        int cc = cntL[i];
        baseL[i] = cc ? bbase[i] + atomicAdd(&bfill[i], cc) : 0;
        cntL[i] = 0;
    }
    __syncthreads();
    for (int e = e0 + t; e < e1; e += 512) {
        int sv = src[e], d = dstv[e];
        int b = d >> 8;
        int r = atomicAdd(&cntL[b], 1);
        tmp[baseL[b] + r] = (uint32)sv | ((uint32)(d & 255) << 16);
    }
}

// ---- L4: per-bucket exact sort (512 threads); emit dinv / rs / ssrc -------
__global__ __launch_bounds__(512) void k_bsort(
    const uint32* __restrict__ tmp, const int* __restrict__ bbase,
    u16* __restrict__ ssrc, int* __restrict__ rs,
    float* __restrict__ dinv, int N)
{
    __shared__ int cnt[256];
    __shared__ int ofs[256];
    int t = threadIdx.x;
    int b = blockIdx.x;
    int base = bbase[b];
    int endb = bbase[b + 1];
    int node0 = b << 8;

    if (t < 256) cnt[t] = 0;
    __syncthreads();
    for (int i = base + t; i < endb; i += 512)
        atomicAdd(&cnt[(tmp[i] >> 16) & 255], 1);
    __syncthreads();
    int v = (t < 256) ? cnt[t] : 0;
    __syncthreads();
    for (int off = 1; off < 256; off <<= 1) {
        int u = (t >= off && t < 256) ? cnt[t - off] : 0;
        __syncthreads();
        if (t < 256) cnt[t] += u;
        __syncthreads();
    }
    if (t < 256) {
        int node = node0 + t;
        if (node < N) {
            dinv[node] = rsqrtf(fmaxf((float)v, 1.0f));
            rs[node] = base + cnt[t];
        }
        ofs[t] = base + cnt[t] - v;
    }
    __syncthreads();
    for (int i = base + t; i < endb; i += 512) {
        uint32 rec = tmp[i];
        int pos = atomicAdd(&ofs[(rec >> 16) & 255], 1);
        ssrc[pos] = (u16)(rec & 0xffffu);
    }
}

// ---- L5: pullg — fused pull1 + gemm2 --------------------------------------
__global__ __launch_bounds__(256) void k_pullg(
    const int* __restrict__ rs, const u16* __restrict__ ssrc,
    const float* __restrict__ dinv, const uint2* __restrict__ h,
    const float* __restrict__ b1, const float* __restrict__ W2,
    u16* __restrict__ h2, int N)
{
    __shared__ float W2T[16 * 132];   // [f][k] pitch 132
    __shared__ float rowbuf[8 * 132]; // [r][k] pitch 132 (float4 pitch 33)
    int t = threadIdx.x;

    for (int g = t; g < 2048; g += 256) {
        int k = g >> 4, f = g & 15;
        W2T[f * 132 + k] = W2[g];
    }

    int wave = t >> 6, lane = t & 63;
    int sub = lane >> 5;
    int rl = lane & 31;
    int rowbase = blockIdx.x * 8;
    int n = rowbase + wave * 2 + sub;
    bool valid = (n < N);
    int nc = valid ? n : 0;
    int start = valid ? ((nc == 0) ? 0 : rs[nc - 1]) : 0;
    int len   = valid ? (rs[nc] - start) : 0;
    float dn  = valid ? dinv[nc] : 0.f;
    int lenMax = max(len, __shfl_xor(len, 32));

    float2 aA[4], aB[4];
    #pragma unroll
    for (int k = 0; k < 4; ++k) {
        aA[k] = (float2){0.f, 0.f};
        aB[k] = (float2){0.f, 0.f};
    }

    for (int tt = 0; tt < lenMax; tt += 4) {
        int s[4];
        uint2 u[4];
        float w[4];
        #pragma unroll
        for (int k = 0; k < 4; ++k) {
            bool act = (tt + k) < len;
            int jj = act ? (start + tt + k) : 0;
            s[k] = (int)ssrc[jj];
            w[k] = act ? 1.f : 0.f;
        }
        #pragma unroll
        for (int k = 0; k < 4; ++k)
            u[k] = h[(size_t)s[k] * 32 + rl];
        #pragma unroll
        for (int k = 0; k < 4; ++k)
            w[k] *= dn * dinv[s[k]];
        #pragma unroll
        for (int k = 0; k < 4; ++k) {
            bffma(aA[k], w[k], u[k].x);
            bffma(aB[k], w[k], u[k].y);
        }
    }

    {
        int r = wave * 2 + sub;
        float4 bb = ((const float4*)b1)[rl];
        float4 v;
        v.x = fmaxf(((aA[0].x + aA[1].x) + (aA[2].x + aA[3].x)) + bb.x, 0.f);
        v.y = fmaxf(((aA[0].y + aA[1].y) + (aA[2].y + aA[3].y)) + bb.y, 0.f);
        v.z = fmaxf(((aB[0].x + aB[1].x) + (aB[2].x + aB[3].x)) + bb.z, 0.f);
        v.w = fmaxf(((aB[0].y + aB[1].y) + (aB[2].y + aB[3].y)) + bb.w, 0.f);
        ((float4*)rowbuf)[r * 33 + rl] = v;
    }
    __syncthreads();

    if (t < 128) {
        int f = t & 15, r = t >> 4;
        const float4* W4 = (const float4*)W2T;
        const float4* rb4 = (const float4*)rowbuf;
        float acc = 0.f;
        #pragma unroll 8
        for (int k4 = 0; k4 < 32; ++k4) {
            float4 w = W4[f * 33 + k4];
            float4 xv = rb4[r * 33 + k4];
            acc = fmaf(xv.x, w.x, acc);
            acc = fmaf(xv.y, w.y, acc);
            acc = fmaf(xv.z, w.z, acc);
            acc = fmaf(xv.w, w.w, acc);
        }
        int rn = rowbase + r;
        if (rn < N) h2[(size_t)rn * 16 + f] = bf16rn(acc);
    }
}

// ---- L6: pull2 + log_softmax, 4-deep unroll -------------------------------
__global__ __launch_bounds__(256) void k_pull2(
    const int* __restrict__ rs, const u16* __restrict__ ssrc,
    const float* __restrict__ dinv, const uint32* __restrict__ h2,
    const float* __restrict__ b2, float* __restrict__ out, int N)
{
    int idx = blockIdx.x * 256 + threadIdx.x;
    int n = idx >> 3;
    if (n >= N) return;
    int c = idx & 7;
    int start = (n == 0) ? 0 : rs[n - 1];
    int len = rs[n] - start;
    float dn = dinv[n];

    float2 a[4];
    #pragma unroll
    for (int k = 0; k < 4; ++k) a[k] = (float2){0.f, 0.f};

    for (int tt = 0; tt < len; tt += 4) {
        int s[4];
        uint32 u[4];
        float w[4];
        #pragma unroll
        for (int k = 0; k < 4; ++k) {
            bool act = (tt + k) < len;
            int jj = act ? (start + tt + k) : 0;   // index 0 always valid
            s[k] = (int)ssrc[jj];
            w[k] = act ? 1.f : 0.f;
        }
        #pragma unroll
        for (int k = 0; k < 4; ++k)
            u[k] = h2[(size_t)s[k] * 8 + c];
        #pragma unroll
        for (int k = 0; k < 4; ++k)
            w[k] *= dn * dinv[s[k]];
        #pragma unroll
        for (int k = 0; k < 4; ++k)
            bffma(a[k], w[k], u[k]);
    }

    float acc0 = (a[0].x + a[1].x) + (a[2].x + a[3].x);
    float acc1 = (a[0].y + a[1].y) + (a[2].y + a[3].y);
    float v0 = acc0 + b2[2 * c];
    float v1 = acc1 + b2[2 * c + 1];
    float m = fmaxf(v0, v1);
    #pragma unroll
    for (int off = 1; off < 8; off <<= 1) m = fmaxf(m, __shfl_xor(m, off));
    float s = expf(v0 - m) + expf(v1 - m);
    #pragma unroll
    for (int off = 1; off < 8; off <<= 1) s += __shfl_xor(s, off);
    float ls = logf(s);
    float2 r = {v0 - m - ls, v1 - m - ls};
    ((float2*)out)[(size_t)n * 8 + c] = r;
}

extern "C" void kernel_launch(void* const* d_in, const int* in_sizes, int n_in,
                              void* d_out, int out_size, void* d_ws, size_t ws_size,
                              hipStream_t stream) {
    const float* x  = (const float*)d_in[0];
    const int*   ei = (const int*)d_in[1];
    const float* W1 = (const float*)d_in[2];
    const float* b1 = (const float*)d_in[3];
    const float* W2 = (const float*)d_in[4];
    const float* b2 = (const float*)d_in[5];
    float* outp = (float*)d_out;

    const int E = in_sizes[1] / 2;
    const int N = in_sizes[0] / 128;   // N=50000 (fits u16 src packing)
    const int NB = (N + 255) >> 8;
    const int NH = (E + EH - 1) / EH;
    const int ntile = (N + 63) / 64;
    const int* src  = ei;
    const int* dstv = ei + E;

    const int Npad = (N + 255) & ~255;
    const int Epad = (E + 255) & ~255;
    int*   gh    = (int*)d_ws;                      // [NBMAX] global hist
    int*   bbase = gh + NBMAX;                      // [NBMAX+1] (+pad)
    int*   bfill = bbase + NBMAX + 256;             // [NBMAX]
    int*   rs    = bfill + NBMAX;                   // [Npad]
    float* dinv  = (float*)(rs + Npad);             // [Npad]
    uint32* tmp  = (uint32*)(dinv + Npad);          // [Epad] packed src|dstlow
    u16*   ssrc  = (u16*)(tmp + Epad);              // [Epad] u16
    uintptr_t hp = ((uintptr_t)(ssrc + Epad) + 255) & ~(uintptr_t)255;
    u16*   h     = (u16*)hp;                        // [Npad*128] bf16
    u16*   h2    = h + (size_t)Npad * 128;          // [Npad*16] bf16

    hipMemsetAsync(gh, 0, NBMAX * sizeof(int), stream);
    k_combo<<<ntile + NH, 256, 0, stream>>>(x, W1, dstv, gh, h, N, E, NB, ntile);
    k_scanB<<<1, 1024, 0, stream>>>(gh, bbase, bfill, NB, E);
    k_partition<<<(E + CHUNK - 1) / CHUNK, 512, 0, stream>>>(src, dstv, bbase,
                                                             bfill, tmp, E, NB);
    k_bsort<<<NB, 512, 0, stream>>>(tmp, bbase, ssrc, rs, dinv, N);
    k_pullg<<<(N + 7) / 8, 256, 0, stream>>>(rs, ssrc, dinv, (const uint2*)h,
                                             b1, W2, h2, N);
    k_pull2<<<(N * 8 + 255) / 256, 256, 0, stream>>>(rs, ssrc, dinv,
                                                     (const uint32*)h2, b2, outp, N);
}